// Round 10
// baseline (14425.415 us; speedup 1.0000x reference)
//
#include <hip/hip_runtime.h>
#include <stdint.h>

typedef unsigned int u32;
typedef unsigned long long u64;
typedef __attribute__((ext_vector_type(8))) short bf16x8;
typedef __attribute__((ext_vector_type(4))) float f32x4;
typedef __attribute__((ext_vector_type(4))) int i32x4;
typedef __attribute__((ext_vector_type(2))) int i32x2;

#define DEV static __device__ __forceinline__

DEV short f2bf(float f){ u32 u=__float_as_uint(f); return (short)((u + 0x7fffu + ((u>>16)&1u))>>16); }
DEV float bf2f(short s){ return __uint_as_float(((u32)(unsigned short)s)<<16); }
DEV float sig_p(float x){ return 1.f/(1.f+expf(-x)); }
DEV float tanh_fast(float x){ float e=__expf(2.f*x); return 1.f-2.f/(e+1.f); }

// ---------------- convert / transpose kernels ----------------

__global__ void cvt1d(const float* __restrict__ in, short* __restrict__ out, int n){
  int i = blockIdx.x*256 + threadIdx.x;
  if (i < n) out[i] = f2bf(in[i]);
}

// in f32 [R][C] -> out bf16 [Cpad][R]
__global__ void tconv(const float* __restrict__ in, short* __restrict__ out, int R, int C, int Cpad){
  __shared__ float t[32][33];
  int tx = threadIdx.x, ty = threadIdx.y;
  int c0 = blockIdx.x*32, r0 = blockIdx.y*32;
#pragma unroll
  for (int j=0;j<4;++j){
    int r = r0 + ty + 8*j, c = c0 + tx;
    t[ty+8*j][tx] = (c < C) ? in[(size_t)r*C + c] : 0.f;
  }
  __syncthreads();
#pragma unroll
  for (int j=0;j<4;++j){
    int oc = c0 + ty + 8*j;
    out[(size_t)oc*R + r0 + tx] = f2bf(t[tx][ty+8*j]);
  }
}

// [s][1536][32] -> [b][1536][128]
__global__ void etrans(const short* __restrict__ in, short* __restrict__ out){
  __shared__ short t[128][33];
  int c = blockIdx.x, tid = threadIdx.x;
#pragma unroll
  for (int i=0;i<16;++i){
    int idx = tid + i*256;
    t[idx>>5][idx&31] = in[((size_t)(idx>>5)*1536 + c)*32 + (idx&31)];
  }
  __syncthreads();
#pragma unroll
  for (int i=0;i<16;++i){
    int idx = tid + i*256;
    out[((size_t)(idx>>7)*1536 + c)*128 + (idx&127)] = t[idx&127][idx>>7];
  }
}

__global__ void embed_k(const int* __restrict__ tok, const float* __restrict__ emb, short* __restrict__ X){
  int row = blockIdx.x;               // (s,b)
  int s = row >> 5, b = row & 31;
  int tv = tok[b*128 + s];
  X[(size_t)row*256 + threadIdx.x] = f2bf(emb[(size_t)tv*256 + threadIdx.x]);
}

// ---------------- MFMA GEMM  C = A[M,K] * BT[Npad][K] ----------------
template<int MODE>
__global__ __launch_bounds__(256) void gemm_k(
  const short* __restrict__ A, const short* __restrict__ BT,
  const float* __restrict__ bias, void* __restrict__ outp,
  float* __restrict__ psum, int Nreal, int K, int Ntot)
{
  const int m0 = blockIdx.y * 128, n0 = blockIdx.x * 128;
  const int tid = threadIdx.x, l = tid & 63, wv = tid >> 6;
  const int wm = wv >> 1, wn = wv & 1;
  __shared__ __align__(16) short As[128*64];
  __shared__ __align__(16) short Bs[128*64];
  f32x4 acc[4][4];
#pragma unroll
  for (int i=0;i<4;++i)
#pragma unroll
    for (int j=0;j<4;++j) acc[i][j] = (f32x4){0.f,0.f,0.f,0.f};

  const int nkb = K >> 6;
  for (int kb=0; kb<nkb; ++kb){
#pragma unroll
    for (int i=0;i<4;++i){
      int si = tid + i*256;
      int row = si >> 3, seg = si & 7;
      u32 off = (u32)(row*128 + seg*16) ^ (u32)((row&7)<<4);
      *(i32x4*)((char*)As + off) = *(const i32x4*)(A + (size_t)(m0+row)*K + kb*64 + seg*8);
      *(i32x4*)((char*)Bs + off) = *(const i32x4*)(BT + (size_t)(n0+row)*K + kb*64 + seg*8);
    }
    __syncthreads();
#pragma unroll
    for (int kt=0; kt<2; ++kt){
      bf16x8 af[4], bfv[4];
      int seg = kt*4 + (l>>4);
#pragma unroll
      for (int f=0; f<4; ++f){
        int ra = wm*64 + f*16 + (l&15);
        af[f]  = *(const bf16x8*)((char*)As + (((u32)(ra*128 + seg*16)) ^ ((u32)(ra&7)<<4)));
        int rb = wn*64 + f*16 + (l&15);
        bfv[f] = *(const bf16x8*)((char*)Bs + (((u32)(rb*128 + seg*16)) ^ ((u32)(rb&7)<<4)));
      }
#pragma unroll
      for (int mf=0; mf<4; ++mf)
#pragma unroll
        for (int nf=0; nf<4; ++nf)
          acc[mf][nf] = __builtin_amdgcn_mfma_f32_16x16x32_bf16(af[mf], bfv[nf], acc[mf][nf], 0,0,0);
    }
    __syncthreads();
  }

  if (MODE == 1){
    short* oT = (short*)outp;
#pragma unroll
    for (int mf=0; mf<4; ++mf){
      int r0 = m0 + wm*64 + mf*16 + ((l>>4)<<2);
      int s = r0 >> 5, b0 = r0 & 31;
#pragma unroll
      for (int nf=0; nf<4; ++nf){
        int col = n0 + wn*64 + nf*16 + (l&15);
        float bv = bias ? bias[col] : 0.f;
        short tmp[4];
#pragma unroll
        for (int j=0;j<4;++j) tmp[j] = f2bf(acc[mf][nf][j] + bv);
        *(i32x2*)(oT + ((size_t)s*Ntot + col)*32 + b0) = *(i32x2*)tmp;
      }
    }
  } else if (MODE == 3){
    short* o = (short*)outp;
#pragma unroll
    for (int mf=0; mf<4; ++mf){
      int r0 = m0 + wm*64 + mf*16 + ((l>>4)<<2);
#pragma unroll
      for (int nf=0; nf<4; ++nf){
        int col = n0 + wn*64 + nf*16 + (l&15);
        if (col < Nreal){
          float bv = bias ? bias[col] : 0.f;
#pragma unroll
          for (int j=0;j<4;++j) o[(size_t)(r0+j)*Nreal + col] = f2bf(acc[mf][nf][j] + bv);
        }
      }
    }
  } else { // MODE 2
    float* o = (float*)outp;
    int ncb = gridDim.x;
    float rs[4][4];
#pragma unroll
    for (int i=0;i<4;++i)
#pragma unroll
      for (int j=0;j<4;++j) rs[i][j]=0.f;
#pragma unroll
    for (int mf=0; mf<4; ++mf){
      int r0 = m0 + wm*64 + mf*16 + ((l>>4)<<2);
      int s = r0 >> 5, b0 = r0 & 31;
#pragma unroll
      for (int nf=0; nf<4; ++nf){
        int col = n0 + wn*64 + nf*16 + (l&15);
        if (col < Nreal){
          float bv = bias[col];
#pragma unroll
          for (int j=0;j<4;++j){
            float e = __expf(acc[mf][nf][j] + bv);
            o[(size_t)((b0+j)*128 + s)*Nreal + col] = e;
            rs[mf][j] += e;
          }
        }
      }
    }
#pragma unroll
    for (int mf=0; mf<4; ++mf)
#pragma unroll
      for (int j=0;j<4;++j){
        float v = rs[mf][j];
        v += __shfl_xor(v,1); v += __shfl_xor(v,2); v += __shfl_xor(v,4); v += __shfl_xor(v,8);
        if ((l&15)==0){
          int r = m0 + wm*64 + mf*16 + ((l>>4)<<2) + j;
          int orow = (r&31)*128 + (r>>5);
          psum[(size_t)orow*(2*ncb) + blockIdx.x*2 + wn] = v;
        }
      }
  }
}

// ---------------- encoder scan: 8 WGs (2 dir x 4), 8 batches each, NO cross-WG sync ----------------
// gx row-major [(s*32+b)][1536] (incl bi). Wh streamed from L2 each step.
__global__ __launch_bounds__(512,1) void enc_scan(
  const short* __restrict__ gxfR, const short* __restrict__ gxbR,
  const short* __restrict__ WhfT, const short* __restrict__ WhbT,
  const float* __restrict__ brf, const float* __restrict__ brb,
  short* __restrict__ encRow, float* __restrict__ hfin)
{
  __shared__ __align__(16) short hbf[16*512];   // A operand, rows 0-7 = batches, XOR-swizzled
  __shared__ float ghL[8][1536];
  __shared__ float brL[1536];
  const int tid = threadIdx.x, wg = blockIdx.x;
  const int dir = wg >> 2, b0 = (wg & 3) * 8;
  const short* gxR = dir ? gxbR : gxfR;
  const short* WT  = dir ? WhbT : WhfT;
  const float* br  = dir ? brb  : brf;
  const int l = tid & 63, wv = tid >> 6;

  for (int i = tid; i < 1536; i += 512) brL[i] = br[i];
  for (int i = tid; i < 8192; i += 512) hbf[i] = 0;
  float hreg[8];
#pragma unroll
  for (int bb=0;bb<8;++bb) hreg[bb] = 0.f;
  __syncthreads();

  for (int t=0; t<128; ++t){
    const int s = dir ? (127-t) : t;
    // prefetch gx for this step (coalesced across tid)
    float pxz[8], pxr[8], pxh[8];
#pragma unroll
    for (int bb=0;bb<8;++bb){
      const short* g = gxR + (size_t)(s*32 + b0 + bb)*1536;
      pxz[bb] = bf2f(g[tid]);
      pxr[bb] = bf2f(g[512 + tid]);
      pxh[bb] = bf2f(g[1024 + tid]);
    }
    // gh = h @ Wh via MFMA (M=16: rows 0-7 batches, 8-15 zero); B streamed from L2
#pragma unroll 1
    for (int i2=0; i2<12; ++i2){
      int nt = wv + 8*i2;
      const short* bp = WT + (size_t)(nt*16 + (l&15))*512 + ((l>>4)<<3);
      bf16x8 bfr[16];
#pragma unroll
      for (int kt=0; kt<16; ++kt) bfr[kt] = *(const bf16x8*)(bp + kt*32);
      f32x4 acc = (f32x4){0.f,0.f,0.f,0.f};
#pragma unroll
      for (int kt=0; kt<16; ++kt){
        int row = l & 15;
        int kb = kt*64 + ((l>>4)<<4);
        bf16x8 af = *(const bf16x8*)((const char*)hbf + row*1024 + (kb ^ ((row&7)<<4)));
        acc = __builtin_amdgcn_mfma_f32_16x16x32_bf16(af, bfr[kt], acc, 0,0,0);
      }
      if (l < 32){              // rows 0-7: row = (l>>4)*4 + r
#pragma unroll
        for (int r=0;r<4;++r) ghL[(l>>4)*4 + r][nt*16 + (l&15)] = acc[r];
      }
    }
    __syncthreads();
    // pointwise: thread = hcol tid, 8 batches
#pragma unroll
    for (int bb=0;bb<8;++bb){
      float gz = ghL[bb][tid]        + brL[tid];
      float gr = ghL[bb][512 + tid]  + brL[512 + tid];
      float gh = ghL[bb][1024 + tid] + brL[1024 + tid];
      float z = sig_p(pxz[bb] + gz);
      float r = sig_p(pxr[bb] + gr);
      float hc = tanhf(pxh[bb] + r*gh);
      float hn = z*hreg[bb] + (1.f-z)*hc;
      hreg[bb] = hn;
      short o = f2bf(hn);
      encRow[(size_t)(s*32 + b0 + bb)*1024 + dir*512 + tid] = o;
      *(short*)((char*)hbf + bb*1024 + ((tid*2) ^ ((bb&7)<<4))) = o;
    }
    __syncthreads();
  }
  if (dir){
#pragma unroll
    for (int bb=0;bb<8;++bb) hfin[(size_t)tid*32 + b0 + bb] = hreg[bb];
  }
}

// ---------------- decoder scan: 32 WGs, ONE batch each, NO cross-WG sync ----------------
// Whd + ENCX streamed from L2 (L2-resident); attention + GRU fully WG-local.
__global__ __launch_bounds__(512,1) void dec_scan(
  const short* __restrict__ gxeR,   // [(t*32+b)][1536] bf16 (incl bi_d)
  const short* __restrict__ encx,   // [b][1536][128] bf16
  const short* __restrict__ WhdT,   // [1536][512] bf16
  const float* __restrict__ brd,
  const short* __restrict__ Wa, const short* __restrict__ Uenc, const float* __restrict__ Va,
  const float* __restrict__ hfin,   // [512][32] f32
  short* __restrict__ decRow)       // [(t*32+b)][512] bf16
{
  __shared__ float hs[512];
  __shared__ __align__(16) short hbf[512];
  __shared__ float ghL[1536];
  __shared__ float gxcL[1536];
  __shared__ float brA[1536];
  __shared__ float whp[128*5];
  __shared__ float whv[128];
  __shared__ float scp[128*5];
  __shared__ float sc[128];
  __shared__ float red[4];
  __shared__ float vL[128];
  __shared__ __align__(16) short abf[128];

  const int tid = threadIdx.x, b = blockIdx.x;
  const int l = tid & 63, wv = tid >> 6;

  u32 wa[64];
  {
    const u32* wp = (const u32*)(Wa + (size_t)(tid&127)*512 + (tid>>7)*128);
#pragma unroll
    for (int i=0;i<64;++i) wa[i] = wp[i];
  }
  u32 ue[16];
  {
    int s = tid & 127, aq = tid >> 7;
    const u32* up = (const u32*)(Uenc + ((size_t)(s*32 + b))*128 + aq*32);
#pragma unroll
    for (int i=0;i<16;++i) ue[i] = up[i];
  }
  if (tid < 128) vL[tid] = Va[tid];
  for (int i = tid; i < 1536; i += 512) brA[i] = brd[i];
  {
    float h0 = hfin[(size_t)tid*32 + b];
    hs[tid] = h0;
    hbf[tid] = f2bf(h0);
  }
  const short* eb = encx + (size_t)b*1536*128;
  const short* WT = WhdT;
  __syncthreads();

  for (int t=0; t<128; ++t){
    // prefetch gx (coalesced)
    const short* g = gxeR + (size_t)(t*32 + b)*1536;
    float gx0 = bf2f(g[tid]);
    float gx1 = bf2f(g[512 + tid]);
    float gx2 = bf2f(g[1024 + tid]);
    // ---- gh = h @ Whd via MFMA (M=1 replicated A from hbf broadcast) ----
#pragma unroll 1
    for (int i2=0; i2<12; ++i2){
      int nt = wv + 8*i2;
      const short* bp = WT + (size_t)(nt*16 + (l&15))*512 + ((l>>4)<<3);
      bf16x8 bfr[16];
#pragma unroll
      for (int kt=0; kt<16; ++kt) bfr[kt] = *(const bf16x8*)(bp + kt*32);
      f32x4 acc = (f32x4){0.f,0.f,0.f,0.f};
#pragma unroll
      for (int kt=0; kt<16; ++kt){
        bf16x8 af = *(const bf16x8*)(hbf + kt*32 + ((l>>4)<<3));
        acc = __builtin_amdgcn_mfma_f32_16x16x32_bf16(af, bfr[kt], acc, 0,0,0);
      }
      if (l < 16) ghL[nt*16 + l] = acc[0];
    }
    // ---- attention (WG-local h) ----
    {
      int a = tid & 127, kq2 = tid >> 7;
      float p = 0.f;
      const float* hp2 = &hs[kq2*128];
#pragma unroll 8
      for (int i=0;i<64;++i){
        u32 w2 = wa[i];
        float2 h2 = *(const float2*)(hp2 + 2*i);
        p += bf2f((short)(w2 & 0xffff))*h2.x + bf2f((short)(w2 >> 16))*h2.y;
      }
      whp[a*5 + kq2] = p;
    }
    __syncthreads();
    if (tid < 128) whv[tid] = whp[tid*5]+whp[tid*5+1]+whp[tid*5+2]+whp[tid*5+3];
    __syncthreads();
    {
      int s = tid & 127, aq = tid >> 7;
      float p = 0.f;
#pragma unroll 4
      for (int i=0;i<16;++i){
        u32 u2 = ue[i];
        int a0 = aq*32 + 2*i;
        p += tanh_fast(whv[a0]   + bf2f((short)(u2 & 0xffff))) * vL[a0];
        p += tanh_fast(whv[a0+1] + bf2f((short)(u2 >> 16)))    * vL[a0+1];
      }
      scp[s*5 + aq] = p;
    }
    __syncthreads();
    if (tid < 128) sc[tid] = scp[tid*5]+scp[tid*5+1]+scp[tid*5+2]+scp[tid*5+3];
    __syncthreads();
    float ev = 0.f;
    if (tid < 128){
      float v = sc[tid], mx = v;
#pragma unroll
      for (int d2=32; d2; d2>>=1) mx = fmaxf(mx, __shfl_xor(mx, d2));
      if ((tid & 63) == 0) red[tid>>6] = mx;
    }
    __syncthreads();
    if (tid < 128){
      float mx = fmaxf(red[0], red[1]);
      ev = __expf(sc[tid] - mx);
      float sm = ev;
#pragma unroll
      for (int d2=32; d2; d2>>=1) sm += __shfl_xor(sm, d2);
      if ((tid & 63) == 0) red[2 + (tid>>6)] = sm;
    }
    __syncthreads();
    if (tid < 128) abf[tid] = f2bf(ev / (red[2] + red[3]));
    __syncthreads();
    // ---- ctx gate-space reduce via MFMA: gxc[col] = sum_s alpha_s * ENCX[b][col][s] ----
#pragma unroll 1
    for (int i2=0; i2<12; ++i2){
      int nt = wv + 8*i2;
      const short* bp = eb + (size_t)(nt*16 + (l&15))*128 + ((l>>4)<<3);
      bf16x8 bfe[4];
#pragma unroll
      for (int kt=0; kt<4; ++kt) bfe[kt] = *(const bf16x8*)(bp + kt*32);
      f32x4 acc = (f32x4){0.f,0.f,0.f,0.f};
#pragma unroll
      for (int kt=0; kt<4; ++kt){
        bf16x8 af = *(const bf16x8*)(abf + kt*32 + ((l>>4)<<3));
        acc = __builtin_amdgcn_mfma_f32_16x16x32_bf16(af, bfe[kt], acc, 0,0,0);
      }
      if (l < 16) gxcL[nt*16 + l] = acc[0];
    }
    __syncthreads();
    // ---- pointwise + state update (all LDS-local) ----
    {
      float z = sig_p(gx0 + gxcL[tid]        + ghL[tid]        + brA[tid]);
      float r = sig_p(gx1 + gxcL[512 + tid]  + ghL[512 + tid]  + brA[512 + tid]);
      float hc = tanhf(gx2 + gxcL[1024 + tid] + r*(ghL[1024 + tid] + brA[1024 + tid]));
      float hp = hs[tid];
      float hn = z*hp + (1.f-z)*hc;
      short o = f2bf(hn);
      hs[tid] = hn;
      hbf[tid] = o;
      decRow[(size_t)(t*32 + b)*512 + tid] = o;
    }
    __syncthreads();
  }
}

// ---------------- softmax finish ----------------
__global__ void scale_rows(float* __restrict__ out, const float* __restrict__ psum,
                           int ncols, int w){
  int r = blockIdx.x;
  __shared__ float ssum[256];
  float s = 0.f;
  for (int i = threadIdx.x; i < w; i += 256) s += psum[(size_t)r*w + i];
  ssum[threadIdx.x] = s; __syncthreads();
  for (int d = 128; d; d >>= 1){
    if (threadIdx.x < d) ssum[threadIdx.x] += ssum[threadIdx.x + d];
    __syncthreads();
  }
  float v = 1.f/ssum[0];
  float* p = out + (size_t)r*ncols;
  for (int i = threadIdx.x; i < ncols; i += 256) p[i] *= v;
}

// ---------------- host ----------------
extern "C" void kernel_launch(void* const* d_in, const int* in_sizes, int n_in,
                              void* d_out, int out_size, void* d_ws, size_t ws_size,
                              hipStream_t stream)
{
  const int*   tokens=(const int*)  d_in[0];
  const float* emb  =(const float*)d_in[1];
  const float* Wx_f =(const float*)d_in[2];
  const float* Wh_f =(const float*)d_in[3];
  const float* bi_f =(const float*)d_in[4];
  const float* br_f =(const float*)d_in[5];
  const float* Wx_b =(const float*)d_in[6];
  const float* Wh_b =(const float*)d_in[7];
  const float* bi_b =(const float*)d_in[8];
  const float* br_b =(const float*)d_in[9];
  const float* W_a  =(const float*)d_in[10];
  const float* U_a  =(const float*)d_in[11];
  const float* V_a  =(const float*)d_in[12];
  const float* Wx_d =(const float*)d_in[13];
  const float* Wh_d =(const float*)d_in[14];
  const float* bi_d =(const float*)d_in[15];
  const float* br_d =(const float*)d_in[16];
  const float* Wo   =(const float*)d_in[17];
  const float* bo   =(const float*)d_in[18];

  const int NV = 32001, NVP = 32128, NCB = 251;

  char* base = (char*)d_ws; size_t off = 0;
  auto alloc = [&](size_t bytes)->char*{
    off = (off + 255) & ~(size_t)255;
    char* p = base + off; off += bytes; return p;
  };
  float* hfin   = (float*)alloc((size_t)512*32*4);
  short* X      = (short*)alloc((size_t)4096*256*2);
  short* WxfT   = (short*)alloc((size_t)1536*256*2);
  short* WxbT   = (short*)alloc((size_t)1536*256*2);
  short* WhfT   = (short*)alloc((size_t)1536*512*2);
  short* WhbT   = (short*)alloc((size_t)1536*512*2);
  short* WhdT   = (short*)alloc((size_t)1536*512*2);
  short* WxeT   = (short*)alloc((size_t)1536*1024*2);
  short* WxcT   = (short*)alloc((size_t)1536*1024*2);
  short* WoT    = (short*)alloc((size_t)NVP*512*2);
  short* UaB    = (short*)alloc((size_t)128*1024*2);
  short* WaB    = (short*)alloc((size_t)128*512*2);
  short* gxfR   = (short*)alloc((size_t)4096*1536*2);    // [(s*32+b)][1536]
  short* gxbR   = (short*)alloc((size_t)4096*1536*2);
  short* encRow = (short*)alloc((size_t)4096*1024*2);
  short* Uenc   = (short*)alloc((size_t)4096*128*2);
  short* gxeR   = (short*)alloc((size_t)4096*1536*2);
  short* encxT1 = (short*)alloc((size_t)128*1536*32*2);
  short* encx   = (short*)alloc((size_t)32*1536*128*2);  // [b][1536][128]
  short* decRow = (short*)alloc((size_t)4096*512*2);
  float* psum   = (float*)alloc((size_t)4096*2*NCB*4);

  // weight conversions (all BT = [N][K] bf16)
  tconv<<<dim3(1536/32,256/32),dim3(32,8),0,stream>>>(Wx_f, WxfT, 256, 1536, 1536);
  tconv<<<dim3(1536/32,256/32),dim3(32,8),0,stream>>>(Wx_b, WxbT, 256, 1536, 1536);
  tconv<<<dim3(1536/32,512/32),dim3(32,8),0,stream>>>(Wh_f, WhfT, 512, 1536, 1536);
  tconv<<<dim3(1536/32,512/32),dim3(32,8),0,stream>>>(Wh_b, WhbT, 512, 1536, 1536);
  tconv<<<dim3(1536/32,512/32),dim3(32,8),0,stream>>>(Wh_d, WhdT, 512, 1536, 1536);
  tconv<<<dim3(1536/32,1024/32),dim3(32,8),0,stream>>>(Wx_d,                    WxeT, 1024, 1536, 1536);
  tconv<<<dim3(1536/32,1024/32),dim3(32,8),0,stream>>>(Wx_d+(size_t)1024*1536,  WxcT, 1024, 1536, 1536);
  tconv<<<dim3(NVP/32,512/32),dim3(32,8),0,stream>>>(Wo, WoT, 512, NV, NVP);
  cvt1d<<<(128*512+255)/256,256,0,stream>>>(W_a, WaB, 128*512);
  cvt1d<<<(128*1024+255)/256,256,0,stream>>>(U_a, UaB, 128*1024);

  embed_k<<<4096,256,0,stream>>>(tokens, emb, X);

  gemm_k<3><<<dim3(12,32),256,0,stream>>>(X, WxfT, bi_f, gxfR, nullptr, 1536, 256, 1536);
  gemm_k<3><<<dim3(12,32),256,0,stream>>>(X, WxbT, bi_b, gxbR, nullptr, 1536, 256, 1536);

  enc_scan<<<8,512,0,stream>>>(gxfR, gxbR, WhfT, WhbT, br_f, br_b, encRow, hfin);

  gemm_k<3><<<dim3(1,32),256,0,stream>>>(encRow, UaB, nullptr, Uenc, nullptr, 128, 1024, 128);
  gemm_k<3><<<dim3(12,32),256,0,stream>>>(encRow, WxeT, bi_d, gxeR, nullptr, 1536, 1024, 1536);
  gemm_k<1><<<dim3(12,32),256,0,stream>>>(encRow, WxcT, nullptr, encxT1, nullptr, 1536, 1024, 1536);
  etrans<<<1536,256,0,stream>>>(encxT1, encx);

  dec_scan<<<32,512,0,stream>>>(gxeR, encx, WhdT, br_d, WaB, Uenc, V_a, hfin, decRow);

  gemm_k<2><<<dim3(NCB,32),256,0,stream>>>(decRow, WoT, bo, d_out, psum, NV, 512, NV);

  scale_rows<<<4096,256,0,stream>>>((float*)d_out, psum, NV, 2*NCB);
}